// Round 23
// baseline (187.794 us; speedup 1.0000x reference)
//
#include <hip/hip_runtime.h>

// PQN soft-quantization: x[32768,1024] f32, c[1024,256] f32 -> out[32768,1024] f32
// D=1024, M=8 subspaces of L=128, K=256 codes, logits scaled by 2*ALPHA=20.
//
// R23: phase-1 A-operand in REGISTERS at 16 waves/CU. R22 (69.6us) is LDS-
// pipe bound (~78% busy: 128 b128 reads/wave-iter + 8.4M conflict cy). The
// per-lane phase-1 csA slice is 64 VGPRs and iteration-invariant; current
// demand is 56 with a 128 cap at 512-thr blocks -> 56+64 ~ 120 fits WITHOUT
// crossing the 128 occupancy cliff (m69: waves halve at 64/128/256).
// R20's version of this idea died because 256-thr hosting (cap 256) let the
// allocator balloon to 192 regs -> 3.5 waves/CU; here the 128 cap forces
// <=128 and 16 waves/CU persist. csA LDS copy deleted -> LDS = csB only
// (64 KB) -> 2 blocks x 8 waves/CU. Phase-1 LDS reads -> 0 (LDS time
// halves); phase-2 unchanged. Chunk loop FULLY UNROLLED (static FA regs);
// R22's two-fence discipline retained. Falsifier: spill -> FETCH > 150 MB.
//
// Per wave-iter (16 samples), per chunk a (64 codes, unrolled):
//   phase 1: acc[4] += FA[a][ct][ks] . bf[ks]        (pure registers)
//   online softmax: chunk max -> rescale acc2/sp
//   phase 2: acc2[8] += csB_lds[:, 64a..] . p_chunk  (LDS, swizzled)
// rho row-permutation makes packed exp words feed phase-2 B verbatim
// (validated R8-R22).

#define D_  1024
#define K_  256
#define L_  128

typedef _Float16 f16;
typedef f16 f16x8 __attribute__((ext_vector_type(8)));
typedef f16 f16x4 __attribute__((ext_vector_type(4)));
typedef float f32x4 __attribute__((ext_vector_type(4)));
typedef unsigned int u32;

// prep: c[(m*128+l)*256 + code] f32 -> ws[m][rho(code)][l] f16 (512 KB)
__global__ __launch_bounds__(128)
void pqn_prep(const float* __restrict__ c, f16* __restrict__ ws) {
    const int b   = blockIdx.x;          // m*256 + code
    const int m   = b >> 8;
    const int cc  = b & 255;
    const int l   = threadIdx.x;         // 0..127
    const int rho = (cc & ~31) | ((cc & 4) << 2) | ((cc & 24) >> 1) | (cc & 3);
    float v = c[(size_t)(m * L_ + l) * K_ + cc];
    ws[((size_t)m * K_ + rho) * L_ + l] = (f16)v;   // 256-B rows, coalesced
}

__global__ __launch_bounds__(512)
void pqn_main(const float* __restrict__ x, const float* __restrict__ c,
              const f16* __restrict__ ws, float* __restrict__ out) {
    __shared__ unsigned char csB[65536];  // [128 l][256 codes] f16, 512-B rows, ^(l&7)<<4

    const int tid  = threadIdx.x;
    const int m    = blockIdx.x >> 6;    // 8 subspaces x 64 blocks
    const int bm   = blockIdx.x & 63;
    const int lane = tid & 63;
    const int w    = tid >> 6;           // wave 0..7
    const int n    = lane & 15;          // sample column
    const int g    = lane >> 4;          // quarter-wave (k-group)

    // ---- stage csB from c (f32 -> f16, swizzled; 512 threads, 8 rounds) ----
    const float* cm = c + (size_t)m * L_ * K_;       // cm[l*256 + k]
    {
        const int R0 = tid >> 6;         // 0..7
        const int f  = tid & 63;         // code quad
        #pragma unroll
        for (int b = 0; b < 8; ++b) {
            int R  = b * 8 + R0;         // 0..63
            int l0 = 2 * R;
            float4 a  = *reinterpret_cast<const float4*>(cm + (size_t)l0 * K_ + 4 * f);
            float4 bb = *reinterpret_cast<const float4*>(cm + (size_t)(l0 + 1) * K_ + 4 * f);
            f16x4 va = {(f16)a.x, (f16)a.y, (f16)a.z, (f16)a.w};
            f16x4 vb = {(f16)bb.x, (f16)bb.y, (f16)bb.z, (f16)bb.w};
            *reinterpret_cast<f16x4*>(csB + l0 * 512       + ((8 * f) ^ ((l0 & 7) << 4))) = va;
            *reinterpret_cast<f16x4*>(csB + (l0 + 1) * 512 + ((8 * f) ^ (((l0 + 1) & 7) << 4))) = vb;
        }
    }

    // ---- load the lane's entire phase-1 A-slice into registers (256 B) ----
    const f16* wsm = ws + (size_t)m * (K_ * L_) + (size_t)n * L_ + 8 * g;
    f16x8 FA[4][4][4];   // [a][ct][ks], iteration-invariant
    #pragma unroll
    for (int a = 0; a < 4; ++a)
        #pragma unroll
        for (int ct = 0; ct < 4; ++ct)
            #pragma unroll
            for (int ks = 0; ks < 4; ++ks)
                FA[a][ct][ks] = *reinterpret_cast<const f16x8*>(
                    wsm + (a * 64 + ct * 16) * L_ + 32 * ks);

    __syncthreads();

    #pragma unroll 1
    for (int it = 0; it < 4; ++it) {
        const int row0 = bm * 512 + it * 128 + w * 16 + n;

        // ---- x load + cvt to f16 fragments + row norm ----
        const float* px = x + (size_t)row0 * D_ + m * L_ + 8 * g;
        float ss = 0.f;
        f16x8 bf[4];
        #pragma unroll
        for (int ks = 0; ks < 4; ++ks) {
            float4 lo = *reinterpret_cast<const float4*>(px + 32 * ks);
            float4 hi = *reinterpret_cast<const float4*>(px + 32 * ks + 4);
            ss = fmaf(lo.x, lo.x, ss); ss = fmaf(lo.y, lo.y, ss);
            ss = fmaf(lo.z, lo.z, ss); ss = fmaf(lo.w, lo.w, ss);
            ss = fmaf(hi.x, hi.x, ss); ss = fmaf(hi.y, hi.y, ss);
            ss = fmaf(hi.z, hi.z, ss); ss = fmaf(hi.w, hi.w, ss);
            bf[ks][0] = (f16)lo.x; bf[ks][1] = (f16)lo.y;
            bf[ks][2] = (f16)lo.z; bf[ks][3] = (f16)lo.w;
            bf[ks][4] = (f16)hi.x; bf[ks][5] = (f16)hi.y;
            bf[ks][6] = (f16)hi.z; bf[ks][7] = (f16)hi.w;
        }
        ss += __shfl_xor(ss, 16);
        ss += __shfl_xor(ss, 32);
        const float fac = 20.0f / fmaxf(sqrtf(ss), 1e-12f);

        // ---- online-softmax fused phase1 -> phase2, 4 chunks (unrolled) ----
        f32x4 acc2[8];
        const f32x4 fzero = {0.f, 0.f, 0.f, 0.f};
        #pragma unroll
        for (int lt = 0; lt < 8; ++lt) acc2[lt] = fzero;
        float mrun = -3.0e38f;
        float sp   = 0.f;

        #pragma unroll
        for (int a = 0; a < 4; ++a) {
            // phase-1 chunk: pure-register MFMA (no loads at all)
            f32x4 acc[4];
            #pragma unroll
            for (int ct = 0; ct < 4; ++ct) acc[ct] = fzero;
            #pragma unroll
            for (int ks = 0; ks < 4; ++ks)
                #pragma unroll
                for (int ct = 0; ct < 4; ++ct)
                    acc[ct] = __builtin_amdgcn_mfma_f32_16x16x32_f16(
                        FA[a][ct][ks], bf[ks], acc[ct], 0, 0, 0);
            __builtin_amdgcn_sched_barrier(0);

            // softmax + pack + phase 2 in one region (csB reads overlap VALU)
            float cmax = -3.0e38f;
            #pragma unroll
            for (int ct = 0; ct < 4; ++ct) {
                acc[ct][0] *= fac; acc[ct][1] *= fac;
                acc[ct][2] *= fac; acc[ct][3] *= fac;
                cmax = fmaxf(cmax, fmaxf(fmaxf(acc[ct][0], acc[ct][1]),
                                         fmaxf(acc[ct][2], acc[ct][3])));
            }
            cmax = fmaxf(cmax, __shfl_xor(cmax, 16));
            cmax = fmaxf(cmax, __shfl_xor(cmax, 32));
            const float mnew = fmaxf(mrun, cmax);
            const float r = __expf(mrun - mnew);
            mrun = mnew;
            sp *= r;
            #pragma unroll
            for (int lt = 0; lt < 8; ++lt) {
                acc2[lt][0] *= r; acc2[lt][1] *= r;
                acc2[lt][2] *= r; acc2[lt][3] *= r;
            }
            u32 P[8];
            #pragma unroll
            for (int ct = 0; ct < 4; ++ct) {
                float p0 = __expf(acc[ct][0] - mrun);
                float p1 = __expf(acc[ct][1] - mrun);
                float p2 = __expf(acc[ct][2] - mrun);
                float p3 = __expf(acc[ct][3] - mrun);
                sp += (p0 + p1) + (p2 + p3);
                P[2 * ct]     = __builtin_bit_cast(u32, __builtin_amdgcn_cvt_pkrtz(p0, p1));
                P[2 * ct + 1] = __builtin_bit_cast(u32, __builtin_amdgcn_cvt_pkrtz(p2, p3));
            }
            #pragma unroll
            for (int j = 0; j < 2; ++j) {
                union { f16x8 v; u32 q[4]; } pb;
                pb.q[0] = P[4 * j + 0]; pb.q[1] = P[4 * j + 1];
                pb.q[2] = P[4 * j + 2]; pb.q[3] = P[4 * j + 3];
                const int ks2 = 2 * a + j;
                #pragma unroll
                for (int lt = 0; lt < 8; ++lt) {
                    f16x8 a2 = *reinterpret_cast<const f16x8*>(
                        csB + (lt * 16 + n) * 512 + ((64 * ks2 + 16 * g) ^ ((n & 7) << 4)));
                    acc2[lt] = __builtin_amdgcn_mfma_f32_16x16x32_f16(a2, pb.v, acc2[lt], 0, 0, 0);
                }
            }
            __builtin_amdgcn_sched_barrier(0);   // chunk end: bound the window
        }

        // ---- final sum reduce + normalized store ----
        sp += __shfl_xor(sp, 16);
        sp += __shfl_xor(sp, 32);
        const float invS = 1.0f / sp;

        float* po = out + (size_t)row0 * D_ + m * L_ + 4 * g;
        #pragma unroll
        for (int lt = 0; lt < 8; ++lt) {
            f32x4 v;
            v[0] = acc2[lt][0] * invS; v[1] = acc2[lt][1] * invS;
            v[2] = acc2[lt][2] * invS; v[3] = acc2[lt][3] * invS;
            *reinterpret_cast<f32x4*>(po + 16 * lt) = v;
        }
    }
}

extern "C" void kernel_launch(void* const* d_in, const int* in_sizes, int n_in,
                              void* d_out, int out_size, void* d_ws, size_t ws_size,
                              hipStream_t stream) {
    const float* x = (const float*)d_in[0];   // [32768, 1024] f32
    const float* c = (const float*)d_in[1];   // [1024, 256]   f32
    float* out = (float*)d_out;               // [32768, 1024] f32
    f16* ws = (f16*)d_ws;                     // 512 KB: [8][256 rho][128] f16
    (void)in_sizes; (void)n_in; (void)out_size; (void)ws_size;

    pqn_prep<<<dim3(2048), dim3(128), 0, stream>>>(c, ws);
    pqn_main<<<dim3(512), dim3(512), 0, stream>>>(x, c, ws, out);
}

// Round 24
// 66.857 us; speedup vs baseline: 2.8089x; 2.8089x over previous
//
#include <hip/hip_runtime.h>

// PQN soft-quantization: x[32768,1024] f32, c[1024,256] f32 -> out[32768,1024] f32
// D=1024, M=8 subspaces of L=128, K=256 codes, logits scaled by 2*ALPHA=20.
//
// R24 = R22 (dual-LDS codebook, 1024-thr, 16 waves/CU, selective fences,
// 69.6us) + two low-risk overlap fixes:
//  (1) x PREFETCH: next iter's 8 float4 loads issue in chunk-1's shadow
//      (~4500 cy of softmax/phase-2 cover) instead of serializing at iter
//      top. xa[8] persists (+32 regs; 56 -> ~90-110 < 128 cap).
//  (2) DEFER-MAX (T13, exact): skip the acc2/sp rescale when
//      __all(cmax <= mrun+8) -- p = exp(z - mrun) <= e^8 fits f16; sum uses
//      the same mrun so normalization stays exact. Saves ~35 VALU ops/chunk
//      for ~3 of 4 chunks.
// R23 lesson (FA-in-regs, 3rd failure): phase-1 operands cannot be hosted
// in registers -- demand 120 + allocator overhead spills at cap 128.
//
// Per wave-iter (16 samples), per chunk a (64 codes):
//   phase 1: acc[4] += csA_lds[rho rows 64a..] . x^T  (free-scheduled b128)
//   fence; [a==1: issue next-iter x loads]; softmax (defer-max);
//   pack ++ phase 2 (csB reads overlap VALU); chunk-end fence
// rho row-permutation makes packed exp words feed phase-2 B verbatim.

#define D_  1024
#define K_  256
#define L_  128

typedef _Float16 f16;
typedef f16 f16x8 __attribute__((ext_vector_type(8)));
typedef f16 f16x4 __attribute__((ext_vector_type(4)));
typedef float f32x4 __attribute__((ext_vector_type(4)));
typedef unsigned int u32;

// prep: c[(m*128+l)*256 + code] f32 -> ws[m][rho(code)][l] f16 (512 KB)
__global__ __launch_bounds__(128)
void pqn_prep(const float* __restrict__ c, f16* __restrict__ ws) {
    const int b   = blockIdx.x;          // m*256 + code
    const int m   = b >> 8;
    const int cc  = b & 255;
    const int l   = threadIdx.x;         // 0..127
    const int rho = (cc & ~31) | ((cc & 4) << 2) | ((cc & 24) >> 1) | (cc & 3);
    float v = c[(size_t)(m * L_ + l) * K_ + cc];
    ws[((size_t)m * K_ + rho) * L_ + l] = (f16)v;   // 256-B rows, coalesced
}

__global__ __launch_bounds__(1024)
void pqn_main(const float* __restrict__ x, const float* __restrict__ c,
              const f16* __restrict__ ws, float* __restrict__ out) {
    __shared__ unsigned char lds[131072];
    unsigned char* csA = lds;            // [256 rho-rows][128 l] f16, 256-B rows, ^(r&7)<<4
    unsigned char* csB = lds + 65536;    // [128 l][256 codes] f16, 512-B rows, ^(l&7)<<4

    const int tid  = threadIdx.x;
    const int m    = blockIdx.x >> 5;    // 8 subspaces x 32 blocks
    const int bm   = blockIdx.x & 31;
    const int lane = tid & 63;
    const int w    = tid >> 6;           // wave 0..15
    const int n    = lane & 15;          // sample column
    const int g    = lane >> 4;          // quarter-wave (k-group)

    // ---- stage csA from ws: swizzled 64-KB copy (1024 threads, 4 rounds) ----
    {
        const f16* wsm0 = ws + (size_t)m * (K_ * L_);
        #pragma unroll
        for (int i = 0; i < 4; ++i) {
            int idx = i * 1024 + tid;    // 0..4095 granules of 16 B
            int r   = idx >> 4;          // rho row 0..255
            int q   = idx & 15;          // 16-B granule within row
            f16x8 v = *reinterpret_cast<const f16x8*>(wsm0 + (size_t)idx * 8);
            *reinterpret_cast<f16x8*>(csA + r * 256 + ((q * 16) ^ ((r & 7) << 4))) = v;
        }
    }
    // ---- stage csB from c (f32 -> f16, swizzled; 1024 threads, 4 rounds) ----
    const float* cm = c + (size_t)m * L_ * K_;       // cm[l*256 + k]
    {
        const int R0 = tid >> 6;         // 0..15
        const int f  = tid & 63;         // code quad
        #pragma unroll
        for (int b = 0; b < 4; ++b) {
            int R  = b * 16 + R0;        // 0..63
            int l0 = 2 * R;
            float4 a  = *reinterpret_cast<const float4*>(cm + (size_t)l0 * K_ + 4 * f);
            float4 bb = *reinterpret_cast<const float4*>(cm + (size_t)(l0 + 1) * K_ + 4 * f);
            f16x4 va = {(f16)a.x, (f16)a.y, (f16)a.z, (f16)a.w};
            f16x4 vb = {(f16)bb.x, (f16)bb.y, (f16)bb.z, (f16)bb.w};
            *reinterpret_cast<f16x4*>(csB + l0 * 512       + ((8 * f) ^ ((l0 & 7) << 4))) = va;
            *reinterpret_cast<f16x4*>(csB + (l0 + 1) * 512 + ((8 * f) ^ (((l0 + 1) & 7) << 4))) = vb;
        }
    }
    __syncthreads();

    // ---- prologue: load it=0's x rows ----
    float4 xa[8];
    {
        const float* px = x + (size_t)(bm * 1024 + w * 16 + n) * D_ + m * L_ + 8 * g;
        #pragma unroll
        for (int ks = 0; ks < 4; ++ks) {
            xa[2 * ks]     = *reinterpret_cast<const float4*>(px + 32 * ks);
            xa[2 * ks + 1] = *reinterpret_cast<const float4*>(px + 32 * ks + 4);
        }
    }

    #pragma unroll 1
    for (int it = 0; it < 4; ++it) {
        const int row0 = bm * 1024 + it * 256 + w * 16 + n;

        // ---- cvt prefetched x to f16 fragments + row norm ----
        float ss = 0.f;
        f16x8 bf[4];
        #pragma unroll
        for (int ks = 0; ks < 4; ++ks) {
            float4 lo = xa[2 * ks], hi = xa[2 * ks + 1];
            ss = fmaf(lo.x, lo.x, ss); ss = fmaf(lo.y, lo.y, ss);
            ss = fmaf(lo.z, lo.z, ss); ss = fmaf(lo.w, lo.w, ss);
            ss = fmaf(hi.x, hi.x, ss); ss = fmaf(hi.y, hi.y, ss);
            ss = fmaf(hi.z, hi.z, ss); ss = fmaf(hi.w, hi.w, ss);
            bf[ks][0] = (f16)lo.x; bf[ks][1] = (f16)lo.y;
            bf[ks][2] = (f16)lo.z; bf[ks][3] = (f16)lo.w;
            bf[ks][4] = (f16)hi.x; bf[ks][5] = (f16)hi.y;
            bf[ks][6] = (f16)hi.z; bf[ks][7] = (f16)hi.w;
        }
        ss += __shfl_xor(ss, 16);
        ss += __shfl_xor(ss, 32);
        const float fac = 20.0f / fmaxf(sqrtf(ss), 1e-12f);

        // ---- online-softmax fused phase1 -> phase2, 4 chunks of 64 codes ----
        f32x4 acc2[8];
        const f32x4 fzero = {0.f, 0.f, 0.f, 0.f};
        #pragma unroll
        for (int lt = 0; lt < 8; ++lt) acc2[lt] = fzero;
        float mrun = -3.0e38f;
        float sp   = 0.f;

        #pragma unroll 1
        for (int a = 0; a < 4; ++a) {
            // phase-1 chunk: 16 ds_reads + 16 MFMAs, free-scheduled
            f32x4 acc[4];
            #pragma unroll
            for (int ct = 0; ct < 4; ++ct) acc[ct] = fzero;
            #pragma unroll
            for (int ks = 0; ks < 4; ++ks) {
                #pragma unroll
                for (int ct = 0; ct < 4; ++ct) {
                    f16x8 af = *reinterpret_cast<const f16x8*>(
                        csA + (a * 64 + ct * 16 + n) * 256 +
                        ((64 * ks + 16 * g) ^ ((n & 7) << 4)));
                    acc[ct] = __builtin_amdgcn_mfma_f32_16x16x32_f16(af, bf[ks], acc[ct], 0, 0, 0);
                }
            }
            __builtin_amdgcn_sched_barrier(0);   // cap the window before phase 2's reads

            // ---- prefetch next iter's x in chunk-1's shadow (TA overlaps DS+VALU) ----
            if (a == 1 && it < 3) {
                const float* pnx = x + (size_t)(row0 + 256) * D_ + m * L_ + 8 * g;
                #pragma unroll
                for (int ks = 0; ks < 4; ++ks) {
                    xa[2 * ks]     = *reinterpret_cast<const float4*>(pnx + 32 * ks);
                    xa[2 * ks + 1] = *reinterpret_cast<const float4*>(pnx + 32 * ks + 4);
                }
            }

            // softmax (defer-max) + pack + phase 2 in one region
            float cmax = -3.0e38f;
            #pragma unroll
            for (int ct = 0; ct < 4; ++ct) {
                acc[ct][0] *= fac; acc[ct][1] *= fac;
                acc[ct][2] *= fac; acc[ct][3] *= fac;
                cmax = fmaxf(cmax, fmaxf(fmaxf(acc[ct][0], acc[ct][1]),
                                         fmaxf(acc[ct][2], acc[ct][3])));
            }
            cmax = fmaxf(cmax, __shfl_xor(cmax, 16));
            cmax = fmaxf(cmax, __shfl_xor(cmax, 32));
            if (!__all(cmax <= mrun + 8.0f)) {   // T13: rescale only when needed
                const float mnew = fmaxf(mrun, cmax);
                const float r = __expf(mrun - mnew);
                mrun = mnew;
                sp *= r;
                #pragma unroll
                for (int lt = 0; lt < 8; ++lt) {
                    acc2[lt][0] *= r; acc2[lt][1] *= r;
                    acc2[lt][2] *= r; acc2[lt][3] *= r;
                }
            }
            u32 P[8];
            #pragma unroll
            for (int ct = 0; ct < 4; ++ct) {
                float p0 = __expf(acc[ct][0] - mrun);
                float p1 = __expf(acc[ct][1] - mrun);
                float p2 = __expf(acc[ct][2] - mrun);
                float p3 = __expf(acc[ct][3] - mrun);
                sp += (p0 + p1) + (p2 + p3);
                P[2 * ct]     = __builtin_bit_cast(u32, __builtin_amdgcn_cvt_pkrtz(p0, p1));
                P[2 * ct + 1] = __builtin_bit_cast(u32, __builtin_amdgcn_cvt_pkrtz(p2, p3));
            }
            #pragma unroll
            for (int j = 0; j < 2; ++j) {
                union { f16x8 v; u32 q[4]; } pb;
                pb.q[0] = P[4 * j + 0]; pb.q[1] = P[4 * j + 1];
                pb.q[2] = P[4 * j + 2]; pb.q[3] = P[4 * j + 3];
                const int ks2 = 2 * a + j;
                #pragma unroll
                for (int lt = 0; lt < 8; ++lt) {
                    f16x8 a2 = *reinterpret_cast<const f16x8*>(
                        csB + (lt * 16 + n) * 512 + ((64 * ks2 + 16 * g) ^ ((n & 7) << 4)));
                    acc2[lt] = __builtin_amdgcn_mfma_f32_16x16x32_f16(a2, pb.v, acc2[lt], 0, 0, 0);
                }
            }
            __builtin_amdgcn_sched_barrier(0);   // chunk end: bound the window
        }

        // ---- final sum reduce + normalized store ----
        sp += __shfl_xor(sp, 16);
        sp += __shfl_xor(sp, 32);
        const float invS = 1.0f / sp;

        float* po = out + (size_t)row0 * D_ + m * L_ + 4 * g;
        #pragma unroll
        for (int lt = 0; lt < 8; ++lt) {
            f32x4 v;
            v[0] = acc2[lt][0] * invS; v[1] = acc2[lt][1] * invS;
            v[2] = acc2[lt][2] * invS; v[3] = acc2[lt][3] * invS;
            *reinterpret_cast<f32x4*>(po + 16 * lt) = v;
        }
    }
}

extern "C" void kernel_launch(void* const* d_in, const int* in_sizes, int n_in,
                              void* d_out, int out_size, void* d_ws, size_t ws_size,
                              hipStream_t stream) {
    const float* x = (const float*)d_in[0];   // [32768, 1024] f32
    const float* c = (const float*)d_in[1];   // [1024, 256]   f32
    float* out = (float*)d_out;               // [32768, 1024] f32
    f16* ws = (f16*)d_ws;                     // 512 KB: [8][256 rho][128] f16
    (void)in_sizes; (void)n_in; (void)out_size; (void)ws_size;

    pqn_prep<<<dim3(2048), dim3(128), 0, stream>>>(c, ws);
    pqn_main<<<dim3(256), dim3(1024), 0, stream>>>(x, c, ws, out);
}